// Round 6
// baseline (462.209 us; speedup 1.0000x reference)
//
#include <hip/hip_runtime.h>
#include <hip/hip_bf16.h>

typedef float    f4v    __attribute__((ext_vector_type(4)));
typedef short    short8 __attribute__((ext_vector_type(8)));
typedef unsigned u2v    __attribute__((ext_vector_type(2)));

constexpr int Bn = 4096, TR = 8;

// ---- split-bf16 helpers ----------------------------------------------------
__device__ inline unsigned cvt2(float x, float y) {
  union { __hip_bfloat162 h; unsigned u; } c;
  c.h = __float22bfloat162_rn(float2{x, y});
  return c.u;   // low16 = bf16(x), high16 = bf16(y)
}
__device__ inline void split_pair(float x, float y, unsigned& hp, unsigned& lp) {
  hp = cvt2(x, y);
  float hx = __uint_as_float(hp << 16);
  float hy = __uint_as_float(hp & 0xffff0000u);
  lp = cvt2(x - hx, y - hy);
}
union S8U { unsigned u[4]; short8 s; };
__device__ inline void split8(const float v[8], short8& hi, short8& lo) {
  S8U h, l;
  #pragma unroll
  for (int d = 0; d < 4; ++d) split_pair(v[2 * d], v[2 * d + 1], h.u[d], l.u[d]);
  hi = h.s; lo = l.s;
}
__device__ inline void split8p(const float* p, short8& hi, short8& lo) {
  f4v a = *(const f4v*)p, b = *(const f4v*)(p + 4);
  float v[8] = {a[0], a[1], a[2], a[3], b[0], b[1], b[2], b[3]};
  split8(v, hi, lo);
}
__device__ inline f4v mfma16(short8 a, short8 b, f4v c) {
  return __builtin_amdgcn_mfma_f32_16x16x32_bf16(a, b, c, 0, 0, 0);
}
__device__ __attribute__((always_inline)) inline f4v gdot8(
    const short8 (&ah)[8], const short8 (&al)[8],
    const short8 (&bh)[8], const short8 (&bl)[8]) {
  f4v c = {0.f, 0.f, 0.f, 0.f};
  #pragma unroll
  for (int s = 0; s < 8; ++s) {
    c = mfma16(ah[s], bh[s], c);
    c = mfma16(al[s], bh[s], c);
    c = mfma16(ah[s], bl[s], c);
  }
  return c;
}

// ---------------------------------------------------------------------------
// k_fused: per-block KAT prep + MLP + 100 DR iterations. TR=8 rows/block,
// 512 blocks x 256 threads -> 2 blocks/CU (LDS 53.25 KB). Lanes l15>=8 are
// zero pads throughout.
// ---------------------------------------------------------------------------
__global__ __launch_bounds__(256, 2) void k_fused(
    const float* __restrict__ x,  const float* __restrict__ bmat,
    const float* __restrict__ W1, const float* __restrict__ b1,
    const float* __restrict__ W2, const float* __restrict__ b2,
    const float* __restrict__ W3, const float* __restrict__ b3,
    const float* __restrict__ A,  const int* __restrict__ n_iter_p,
    float* __restrict__ out) {

  __shared__ __align__(16) float    ubuf[8192];    // As[32][256] | MLP scratch
  __shared__ __align__(16) unsigned zfrag[4096];   // prep: Gm[32][68]
  __shared__ __align__(16) unsigned rfrag[1024];   // prep: GinvL[32][32]

  const int t = threadIdx.x;
  const int lane = t & 63, wv = t >> 6, quad = lane >> 4, l15 = lane & 15;
  const int row0 = blockIdx.x * TR;
  const int T = wv & 1, kh = wv >> 1;

  float* As    = ubuf;
  float* Gm    = (float*)zfrag;   // [32][68] augmented [G|I]
  float* GinvL = (float*)rfrag;   // [32][32]

  // ---- stage A into LDS ----
  for (int i = t; i < 2048; i += 256)
    ((f4v*)As)[i] = ((const f4v*)A)[i];
  __syncthreads();

  // ---- G = A A^T (+ eps I) via split-bf16 MFMA; wave = tile (Tm=T, Tn=kh) ---
  {
    short8 afh[2][8], afl[2][8];
    #pragma unroll
    for (int tt = 0; tt < 2; ++tt)
      #pragma unroll
      for (int s = 0; s < 8; ++s)
        split8p(As + (l15 + 16 * tt) * 256 + 32 * s + 8 * quad,
                afh[tt][s], afl[tt][s]);
    f4v cg;
    if      (wv == 0) cg = gdot8(afh[0], afl[0], afh[0], afl[0]);
    else if (wv == 1) cg = gdot8(afh[1], afl[1], afh[0], afl[0]);
    else if (wv == 2) cg = gdot8(afh[0], afl[0], afh[1], afl[1]);
    else              cg = gdot8(afh[1], afl[1], afh[1], afl[1]);
    #pragma unroll
    for (int r = 0; r < 4; ++r) {
      int gi = 16 * T + 4 * quad + r, gj = 16 * kh + l15;
      Gm[gi * 68 + gj]      = cg[r] + (gi == gj ? 1e-6f : 0.f);
      Gm[gi * 68 + 32 + gj] = (gi == gj) ? 1.f : 0.f;
    }
  }
  __syncthreads();

  // ---- Gauss-Jordan on wave 0: lane = augmented column, fully unrolled -----
  if (wv == 0) {
    float gcol[32];
    #pragma unroll
    for (int i = 0; i < 32; ++i) gcol[i] = Gm[i * 68 + lane];
    #pragma unroll
    for (int k = 0; k < 32; ++k) {
      float ckk  = __shfl(gcol[k], k);   // G[k][k] (readlane: k is literal)
      float ipiv = 1.f / ckk;
      float pivj = gcol[k] * ipiv;       // scaled pivot-row elem, own column
      gcol[k] = pivj;
      #pragma unroll
      for (int i = 0; i < 32; ++i) {
        if (i == k) continue;
        float cki = __shfl(gcol[i], k);  // pivot-column elem G[i][k]
        gcol[i] = fmaf(-cki, pivj, gcol[i]);
      }
    }
    if (lane >= 32) {                    // lanes 32..63 hold Ginv columns
      #pragma unroll
      for (int i = 0; i < 32; ++i) GinvL[i * 32 + (lane - 32)] = gcol[i];
    }
  }
  __syncthreads();

  // ---- kan fragments: KAT[n][m] = sum_p A[p][n] * Ginv[p][m] (Ginv sym) ----
  short8 kanh[4], kanl[4];
  #pragma unroll
  for (int u = 0; u < 4; ++u) {
    const int n = 16 * (4 * wv + u) + l15;
    float acc[8];
    #pragma unroll
    for (int j = 0; j < 8; ++j) acc[j] = 0.f;
    for (int p = 0; p < 32; ++p) {
      float av = As[p * 256 + n];
      f4v g0 = *(const f4v*)&GinvL[p * 32 + 8 * quad];
      f4v g1 = *(const f4v*)&GinvL[p * 32 + 8 * quad + 4];
      acc[0] = fmaf(av, g0[0], acc[0]); acc[1] = fmaf(av, g0[1], acc[1]);
      acc[2] = fmaf(av, g0[2], acc[2]); acc[3] = fmaf(av, g0[3], acc[3]);
      acc[4] = fmaf(av, g1[0], acc[4]); acc[5] = fmaf(av, g1[1], acc[5]);
      acc[6] = fmaf(av, g1[2], acc[6]); acc[7] = fmaf(av, g1[3], acc[7]);
    }
    split8(acc, kanh[u], kanl[u]);
  }

  // ---- phase-A fragments from As LDS ----
  short8 aah[4], aal[4];
  #pragma unroll
  for (int s = 0; s < 4; ++s)
    split8p(As + (l15 + 16 * T) * 256 + 128 * kh + 32 * s + 8 * quad,
            aah[s], aal[s]);

  f4v binit = {0.f, 0.f, 0.f, 0.f};
  if (wv < 2 && l15 < 8) {   // kh==0 carries -b; pad rows get 0
    f4v bv = *(const f4v*)&bmat[(size_t)(row0 + l15) * 32 + 16 * T + 4 * quad];
    binit = -bv;
  }
  __syncthreads();   // all As/GinvL reads done; ubuf free for MLP

  // ---- MLP: 8 rows, 2 rows/wave ----
  float* xs = ubuf;             // [8][132]
  float* h1 = ubuf + 1056;      // [8][208]
  float* h2 = ubuf + 2720;      // [8][208]
  float* ys = ubuf;             // [8][260] (xs+h1 dead)

  {
    int r = t >> 5, c4 = t & 31;
    *(f4v*)&xs[r * 132 + 4 * c4] = *(const f4v*)&x[(size_t)(row0 + r) * 128 + 4 * c4];
  }
  __syncthreads();

  {
    const int rg = wv, oc = lane;
    const bool g3 = (oc < 8);
    float acc[4][2];

    // L1: 128 -> 200, relu
    #pragma unroll
    for (int oi = 0; oi < 4; ++oi) { acc[oi][0] = 0.f; acc[oi][1] = 0.f; }
    for (int k4 = 0; k4 < 32; ++k4) {
      f4v xv0 = *(const f4v*)&xs[(2 * rg + 0) * 132 + 4 * k4];
      f4v xv1 = *(const f4v*)&xs[(2 * rg + 1) * 132 + 4 * k4];
      #pragma unroll
      for (int kk = 0; kk < 4; ++kk) {
        const float* wr = W1 + (4 * k4 + kk) * 200 + oc;
        float w0 = wr[0], w1c = wr[64], w2c = wr[128];
        float w3c = g3 ? wr[192] : 0.f;
        acc[0][0] = fmaf(xv0[kk], w0, acc[0][0]);  acc[0][1] = fmaf(xv1[kk], w0, acc[0][1]);
        acc[1][0] = fmaf(xv0[kk], w1c, acc[1][0]); acc[1][1] = fmaf(xv1[kk], w1c, acc[1][1]);
        acc[2][0] = fmaf(xv0[kk], w2c, acc[2][0]); acc[2][1] = fmaf(xv1[kk], w2c, acc[2][1]);
        acc[3][0] = fmaf(xv0[kk], w3c, acc[3][0]); acc[3][1] = fmaf(xv1[kk], w3c, acc[3][1]);
      }
    }
    #pragma unroll
    for (int oi = 0; oi < 4; ++oi) {
      if (oi == 3 && !g3) continue;
      float bb = b1[oc + 64 * oi];
      h1[(2 * rg + 0) * 208 + oc + 64 * oi] = fmaxf(acc[oi][0] + bb, 0.f);
      h1[(2 * rg + 1) * 208 + oc + 64 * oi] = fmaxf(acc[oi][1] + bb, 0.f);
    }
    __syncthreads();

    // L2: 200 -> 200, relu
    #pragma unroll
    for (int oi = 0; oi < 4; ++oi) { acc[oi][0] = 0.f; acc[oi][1] = 0.f; }
    for (int k4 = 0; k4 < 50; ++k4) {
      f4v xv0 = *(const f4v*)&h1[(2 * rg + 0) * 208 + 4 * k4];
      f4v xv1 = *(const f4v*)&h1[(2 * rg + 1) * 208 + 4 * k4];
      #pragma unroll
      for (int kk = 0; kk < 4; ++kk) {
        const float* wr = W2 + (4 * k4 + kk) * 200 + oc;
        float w0 = wr[0], w1c = wr[64], w2c = wr[128];
        float w3c = g3 ? wr[192] : 0.f;
        acc[0][0] = fmaf(xv0[kk], w0, acc[0][0]);  acc[0][1] = fmaf(xv1[kk], w0, acc[0][1]);
        acc[1][0] = fmaf(xv0[kk], w1c, acc[1][0]); acc[1][1] = fmaf(xv1[kk], w1c, acc[1][1]);
        acc[2][0] = fmaf(xv0[kk], w2c, acc[2][0]); acc[2][1] = fmaf(xv1[kk], w2c, acc[2][1]);
        acc[3][0] = fmaf(xv0[kk], w3c, acc[3][0]); acc[3][1] = fmaf(xv1[kk], w3c, acc[3][1]);
      }
    }
    #pragma unroll
    for (int oi = 0; oi < 4; ++oi) {
      if (oi == 3 && !g3) continue;
      float bb = b2[oc + 64 * oi];
      h2[(2 * rg + 0) * 208 + oc + 64 * oi] = fmaxf(acc[oi][0] + bb, 0.f);
      h2[(2 * rg + 1) * 208 + oc + 64 * oi] = fmaxf(acc[oi][1] + bb, 0.f);
    }
    __syncthreads();

    // L3: 200 -> 256 (no relu) -> ys
    #pragma unroll
    for (int oi = 0; oi < 4; ++oi) { acc[oi][0] = 0.f; acc[oi][1] = 0.f; }
    for (int k4 = 0; k4 < 50; ++k4) {
      f4v xv0 = *(const f4v*)&h2[(2 * rg + 0) * 208 + 4 * k4];
      f4v xv1 = *(const f4v*)&h2[(2 * rg + 1) * 208 + 4 * k4];
      #pragma unroll
      for (int kk = 0; kk < 4; ++kk) {
        const float* wr = W3 + (4 * k4 + kk) * 256 + oc;
        float w0 = wr[0], w1c = wr[64], w2c = wr[128], w3c = wr[192];
        acc[0][0] = fmaf(xv0[kk], w0, acc[0][0]);  acc[0][1] = fmaf(xv1[kk], w0, acc[0][1]);
        acc[1][0] = fmaf(xv0[kk], w1c, acc[1][0]); acc[1][1] = fmaf(xv1[kk], w1c, acc[1][1]);
        acc[2][0] = fmaf(xv0[kk], w2c, acc[2][0]); acc[2][1] = fmaf(xv1[kk], w2c, acc[2][1]);
        acc[3][0] = fmaf(xv0[kk], w3c, acc[3][0]); acc[3][1] = fmaf(xv1[kk], w3c, acc[3][1]);
      }
    }
    __syncthreads();   // reads of h2/xs done before ys overlays ubuf
    #pragma unroll
    for (int oi = 0; oi < 4; ++oi) {
      float bb = b3[oc + 64 * oi];
      ys[(2 * rg + 0) * 260 + oc + 64 * oi] = acc[oi][0] + bb;
      ys[(2 * rg + 1) * 260 + oc + 64 * oi] = acc[oi][1] + bb;
    }
  }
  __syncthreads();

  // ---- zfrag write offsets (from phase-B C layout, derived from U alone) ---
  int zoff[4];
  #pragma unroll
  for (int u = 0; u < 4; ++u) {
    const int U = 4 * wv + u;
    const int qp = 2 * (U & 1) + (quad >> 1);
    zoff[u] = (((U >> 3) * 4 + ((U >> 1) & 3)) * 2) * 256
              + qp * 64 + l15 * 4 + 2 * (quad & 1);
  }

  // ---- init z registers from y; publish zfrag (pad lanes write zeros) ----
  float zr[4][4];
  #pragma unroll
  for (int u = 0; u < 4; ++u) {
    const int U = 4 * wv + u;
    f4v yv = *(const f4v*)&ys[l15 * 260 + 16 * U + 4 * quad];
    #pragma unroll
    for (int r = 0; r < 4; ++r) zr[u][r] = (l15 < 8) ? yv[r] : 0.f;
    unsigned h0, l0, h1_, l1_;
    split_pair(zr[u][0], zr[u][1], h0, l0);
    split_pair(zr[u][2], zr[u][3], h1_, l1_);
    u2v hv; hv[0] = h0; hv[1] = h1_;
    u2v lv; lv[0] = l0; lv[1] = l1_;
    *(u2v*)&zfrag[zoff[u]] = hv;
    *(u2v*)&zfrag[zoff[u] + 256] = lv;
  }
  __syncthreads();

  const int niter = n_iter_p[0];

  for (int it = 0; it <= niter; ++it) {
    // ======== Phase A (all 4 waves): partial r^T = A z^T - b^T ========
    {
      short8 zfh[4], zfl[4];
      #pragma unroll
      for (int s = 0; s < 4; ++s) {
        zfh[s] = *(const short8*)&zfrag[((kh * 4 + s) * 2 + 0) * 256 + lane * 4];
        zfl[s] = *(const short8*)&zfrag[((kh * 4 + s) * 2 + 1) * 256 + lane * 4];
      }
      f4v c0 = binit, c1 = {0.f, 0.f, 0.f, 0.f};
      #pragma unroll
      for (int s = 0; s < 4; ++s) {
        f4v cc = (s & 1) ? c1 : c0;
        cc = mfma16(aah[s], zfh[s], cc);
        cc = mfma16(aal[s], zfh[s], cc);
        cc = mfma16(aah[s], zfl[s], cc);
        if (s & 1) c1 = cc; else c0 = cc;
      }
      f4v rA = c0 + c1;
      unsigned h0, l0, h1_, l1_;
      split_pair(rA[0], rA[1], h0, l0);
      split_pair(rA[2], rA[3], h1_, l1_);
      const int lanep = (2 * T + (quad >> 1)) * 16 + l15;
      const int rb = kh * 512 + lanep * 4 + 2 * (quad & 1);
      u2v hv; hv[0] = h0; hv[1] = h1_;
      u2v lv; lv[0] = l0; lv[1] = l1_;
      *(u2v*)&rfrag[rb] = hv;
      *(u2v*)&rfrag[rb + 256] = lv;
    }
    __syncthreads();

    // ======== Phase B: w^T = KA^T r^T for U = 4wv..4wv+3 ========
    const short8 rh0 = *(const short8*)&rfrag[0 * 256 + lane * 4];
    const short8 rl0 = *(const short8*)&rfrag[1 * 256 + lane * 4];
    const short8 rh1 = *(const short8*)&rfrag[2 * 256 + lane * 4];
    const short8 rl1 = *(const short8*)&rfrag[3 * 256 + lane * 4];
    f4v cB[4];
    #pragma unroll
    for (int u = 0; u < 4; ++u) {
      f4v cc = {0.f, 0.f, 0.f, 0.f};
      cc = mfma16(kanh[u], rh0, cc);
      cc = mfma16(kanl[u], rh0, cc);
      cc = mfma16(kanh[u], rl0, cc);
      cc = mfma16(kanh[u], rh1, cc);
      cc = mfma16(kanl[u], rh1, cc);
      cc = mfma16(kanh[u], rl1, cc);
      cB[u] = cc;
    }

    if (it < niter) {
      #pragma unroll
      for (int u = 0; u < 4; ++u) {
        #pragma unroll
        for (int r = 0; r < 4; ++r) {
          float z = zr[u][r], wvv = cB[u][r];
          float vv = fminf(fmaxf(z - 2.f * wvv, 0.f), 1.f);  // clip(2u - z)
          zr[u][r] = fmaf(1.7f, vv - z + wvv, z);            // z += 1.7*(v-u)
        }
        unsigned h0, l0, h1_, l1_;
        split_pair(zr[u][0], zr[u][1], h0, l0);
        split_pair(zr[u][2], zr[u][3], h1_, l1_);
        u2v hv; hv[0] = h0; hv[1] = h1_;
        u2v lv; lv[0] = l0; lv[1] = l1_;
        *(u2v*)&zfrag[zoff[u]] = hv;
        *(u2v*)&zfrag[zoff[u] + 256] = lv;
      }
      __syncthreads();
    } else {
      if (l15 < 8) {
        #pragma unroll
        for (int u = 0; u < 4; ++u) {
          const int U = 4 * wv + u;
          f4v ov;
          #pragma unroll
          for (int r = 0; r < 4; ++r) ov[r] = zr[u][r] - cB[u][r];
          *(f4v*)&out[(size_t)(row0 + l15) * 256 + 16 * U + 4 * quad] = ov;
        }
      }
    }
  }
}

// ---------------------------------------------------------------------------
extern "C" void kernel_launch(void* const* d_in, const int* in_sizes, int n_in,
                              void* d_out, int out_size, void* d_ws, size_t ws_size,
                              hipStream_t stream) {
  const float* x    = (const float*)d_in[0];
  const float* bmat = (const float*)d_in[1];
  const float* W1   = (const float*)d_in[2];
  const float* b1   = (const float*)d_in[3];
  const float* W2   = (const float*)d_in[4];
  const float* b2   = (const float*)d_in[5];
  const float* W3   = (const float*)d_in[6];
  const float* b3   = (const float*)d_in[7];
  const float* A    = (const float*)d_in[8];
  const int*  n_it  = (const int*)d_in[10];
  float* out = (float*)d_out;

  hipLaunchKernelGGL(k_fused, dim3(Bn / TR), dim3(256), 0, stream,
                     x, bmat, W1, b1, W2, b2, W3, b3, A, n_it, out);
}

// Round 7
// 274.661 us; speedup vs baseline: 1.6828x; 1.6828x over previous
//
#include <hip/hip_runtime.h>
#include <hip/hip_bf16.h>

typedef float    f4v    __attribute__((ext_vector_type(4)));
typedef short    short8 __attribute__((ext_vector_type(8)));
typedef unsigned u2v    __attribute__((ext_vector_type(2)));

constexpr int Bn = 4096, TR = 8;

// ---- split-bf16 helpers ----------------------------------------------------
__device__ inline unsigned cvt2(float x, float y) {
  union { __hip_bfloat162 h; unsigned u; } c;
  c.h = __float22bfloat162_rn(float2{x, y});
  return c.u;   // low16 = bf16(x), high16 = bf16(y)
}
__device__ inline void split_pair(float x, float y, unsigned& hp, unsigned& lp) {
  hp = cvt2(x, y);
  float hx = __uint_as_float(hp << 16);
  float hy = __uint_as_float(hp & 0xffff0000u);
  lp = cvt2(x - hx, y - hy);
}
union S8U { unsigned u[4]; short8 s; };
__device__ inline void split8(const float v[8], short8& hi, short8& lo) {
  S8U h, l;
  #pragma unroll
  for (int d = 0; d < 4; ++d) split_pair(v[2 * d], v[2 * d + 1], h.u[d], l.u[d]);
  hi = h.s; lo = l.s;
}
__device__ inline void split8p(const float* p, short8& hi, short8& lo) {
  f4v a = *(const f4v*)p, b = *(const f4v*)(p + 4);
  float v[8] = {a[0], a[1], a[2], a[3], b[0], b[1], b[2], b[3]};
  split8(v, hi, lo);
}
__device__ inline f4v mfma16(short8 a, short8 b, f4v c) {
  return __builtin_amdgcn_mfma_f32_16x16x32_bf16(a, b, c, 0, 0, 0);
}
__device__ __attribute__((always_inline)) inline f4v gdot8(
    const short8 (&ah)[8], const short8 (&al)[8],
    const short8 (&bh)[8], const short8 (&bl)[8]) {
  f4v c = {0.f, 0.f, 0.f, 0.f};
  #pragma unroll
  for (int s = 0; s < 8; ++s) {
    c = mfma16(ah[s], bh[s], c);
    c = mfma16(al[s], bh[s], c);
    c = mfma16(ah[s], bl[s], c);
  }
  return c;
}

// ---------------------------------------------------------------------------
// k_prep: KAT[n][m] = (inv(A A^T + 1e-6 I) @ A)^T -> d_ws. 1 block, 256 thr.
// G via split-bf16 MFMA; Gauss-Jordan on wave 0 via unrolled shuffles
// (zero barriers inside GJ); KAT one column per thread.
// ---------------------------------------------------------------------------
__global__ __launch_bounds__(256) void k_prep(const float* __restrict__ A,
                                              float* __restrict__ KAT) {
  __shared__ __align__(16) float As[32 * 256];
  __shared__ float Gm[32 * 68];
  __shared__ float GinvL[32 * 32];

  const int t = threadIdx.x;
  const int lane = t & 63, wv = t >> 6, quad = lane >> 4, l15 = lane & 15;
  const int T = wv & 1, kh = wv >> 1;

  for (int i = t; i < 2048; i += 256)
    ((f4v*)As)[i] = ((const f4v*)A)[i];
  __syncthreads();

  // G = A A^T (+ eps I): wave = 16x16 tile (rows 16T.., cols 16kh..)
  {
    short8 afh[2][8], afl[2][8];
    #pragma unroll
    for (int tt = 0; tt < 2; ++tt)
      #pragma unroll
      for (int s = 0; s < 8; ++s)
        split8p(As + (l15 + 16 * tt) * 256 + 32 * s + 8 * quad,
                afh[tt][s], afl[tt][s]);
    f4v cg;
    if      (wv == 0) cg = gdot8(afh[0], afl[0], afh[0], afl[0]);
    else if (wv == 1) cg = gdot8(afh[1], afl[1], afh[0], afl[0]);
    else if (wv == 2) cg = gdot8(afh[0], afl[0], afh[1], afl[1]);
    else              cg = gdot8(afh[1], afl[1], afh[1], afl[1]);
    #pragma unroll
    for (int r = 0; r < 4; ++r) {
      int gi = 16 * T + 4 * quad + r, gj = 16 * kh + l15;
      Gm[gi * 68 + gj]      = cg[r] + (gi == gj ? 1e-6f : 0.f);
      Gm[gi * 68 + 32 + gj] = (gi == gj) ? 1.f : 0.f;
    }
  }
  __syncthreads();

  // Gauss-Jordan on wave 0: lane = augmented column, fully unrolled
  if (wv == 0) {
    float gcol[32];
    #pragma unroll
    for (int i = 0; i < 32; ++i) gcol[i] = Gm[i * 68 + lane];
    #pragma unroll
    for (int k = 0; k < 32; ++k) {
      float ckk  = __shfl(gcol[k], k);
      float ipiv = 1.f / ckk;
      float pivj = gcol[k] * ipiv;
      gcol[k] = pivj;
      #pragma unroll
      for (int i = 0; i < 32; ++i) {
        if (i == k) continue;
        float cki = __shfl(gcol[i], k);
        gcol[i] = fmaf(-cki, pivj, gcol[i]);
      }
    }
    if (lane >= 32) {
      #pragma unroll
      for (int i = 0; i < 32; ++i) GinvL[i * 32 + (lane - 32)] = gcol[i];
    }
  }
  __syncthreads();

  // KAT[n=t][m] = sum_p As[p][n] * Ginv[p][m]
  {
    float res[32];
    #pragma unroll
    for (int m = 0; m < 32; ++m) res[m] = 0.f;
    for (int p = 0; p < 32; ++p) {
      float av = As[p * 256 + t];
      #pragma unroll
      for (int m4 = 0; m4 < 8; ++m4) {
        f4v g = *(const f4v*)&GinvL[p * 32 + 4 * m4];
        res[4 * m4 + 0] = fmaf(av, g[0], res[4 * m4 + 0]);
        res[4 * m4 + 1] = fmaf(av, g[1], res[4 * m4 + 1]);
        res[4 * m4 + 2] = fmaf(av, g[2], res[4 * m4 + 2]);
        res[4 * m4 + 3] = fmaf(av, g[3], res[4 * m4 + 3]);
      }
    }
    #pragma unroll
    for (int m4 = 0; m4 < 8; ++m4) {
      f4v v = {res[4 * m4], res[4 * m4 + 1], res[4 * m4 + 2], res[4 * m4 + 3]};
      *(f4v*)&KAT[t * 32 + 4 * m4] = v;
    }
  }
}

// ---------------------------------------------------------------------------
// k_main: 512 threads (8 waves), TR=8, grid 512 -> 2 blocks/CU (LDS 37.5 KB).
// Pad lanes l15>=8 carry exact zeros end-to-end.
// Phase A (waves 0-3): (T=wv&1, kh=wv>>1): partial r^T = A z^T - b^T, 12 MFMA.
// Phase B (all 8): wave owns n-tiles U=2wv,2wv+1: w^T = KA^T r^T, 12 MFMA;
// z update in registers; zfrag republished in B-op fragment order.
// ---------------------------------------------------------------------------
__global__ __launch_bounds__(512, 4) void k_main(
    const float* __restrict__ x,  const float* __restrict__ bmat,
    const float* __restrict__ W1, const float* __restrict__ b1,
    const float* __restrict__ W2, const float* __restrict__ b2,
    const float* __restrict__ W3, const float* __restrict__ b3,
    const float* __restrict__ A,  const float* __restrict__ KAT,
    const int* __restrict__ n_iter_p, float* __restrict__ out) {

  __shared__ __align__(16) float    ubuf[4384];    // MLP scratch; later y[8][260]
  __shared__ __align__(16) unsigned zfrag[4096];   // [kh][s][hi/lo][512B frag]
  __shared__ __align__(16) unsigned rfrag[1024];   // [kh][hi/lo][512B frag]

  const int t = threadIdx.x;
  const int lane = t & 63, wv = t >> 6, quad = lane >> 4, l15 = lane & 15;
  const int row0 = blockIdx.x * TR;
  const int T = wv & 1, kh = wv >> 1;

  float* xs = ubuf;            // [8][132]
  float* h1 = ubuf + 1056;     // [8][208]
  float* h2 = ubuf + 2720;     // [8][208]
  float* ys = ubuf;            // [8][260] (xs+h1 dead by then)

  if (t < 256) {
    int r = t >> 5, c4 = t & 31;
    *(f4v*)&xs[r * 132 + 4 * c4] = *(const f4v*)&x[(size_t)(row0 + r) * 128 + 4 * c4];
  }
  __syncthreads();

  // ---- MLP: 1 row per wave ----
  {
    const int rg = wv, oc = lane;
    const bool g3 = (oc < 8);    // HID=200: col oc+192 valid iff oc<8
    float acc[4];

    // L1: 128 -> 200, relu
    #pragma unroll
    for (int oi = 0; oi < 4; ++oi) acc[oi] = 0.f;
    for (int k4 = 0; k4 < 32; ++k4) {
      f4v xv = *(const f4v*)&xs[rg * 132 + 4 * k4];
      #pragma unroll
      for (int kk = 0; kk < 4; ++kk) {
        const float* wr = W1 + (4 * k4 + kk) * 200 + oc;
        acc[0] = fmaf(xv[kk], wr[0], acc[0]);
        acc[1] = fmaf(xv[kk], wr[64], acc[1]);
        acc[2] = fmaf(xv[kk], wr[128], acc[2]);
        acc[3] = fmaf(xv[kk], g3 ? wr[192] : 0.f, acc[3]);
      }
    }
    #pragma unroll
    for (int oi = 0; oi < 4; ++oi) {
      if (oi == 3 && !g3) continue;
      h1[rg * 208 + oc + 64 * oi] = fmaxf(acc[oi] + b1[oc + 64 * oi], 0.f);
    }
    __syncthreads();

    // L2: 200 -> 200, relu
    #pragma unroll
    for (int oi = 0; oi < 4; ++oi) acc[oi] = 0.f;
    for (int k4 = 0; k4 < 50; ++k4) {
      f4v xv = *(const f4v*)&h1[rg * 208 + 4 * k4];
      #pragma unroll
      for (int kk = 0; kk < 4; ++kk) {
        const float* wr = W2 + (4 * k4 + kk) * 200 + oc;
        acc[0] = fmaf(xv[kk], wr[0], acc[0]);
        acc[1] = fmaf(xv[kk], wr[64], acc[1]);
        acc[2] = fmaf(xv[kk], wr[128], acc[2]);
        acc[3] = fmaf(xv[kk], g3 ? wr[192] : 0.f, acc[3]);
      }
    }
    #pragma unroll
    for (int oi = 0; oi < 4; ++oi) {
      if (oi == 3 && !g3) continue;
      h2[rg * 208 + oc + 64 * oi] = fmaxf(acc[oi] + b2[oc + 64 * oi], 0.f);
    }
    __syncthreads();

    // L3: 200 -> 256 (no relu) -> ys
    #pragma unroll
    for (int oi = 0; oi < 4; ++oi) acc[oi] = 0.f;
    for (int k4 = 0; k4 < 50; ++k4) {
      f4v xv = *(const f4v*)&h2[rg * 208 + 4 * k4];
      #pragma unroll
      for (int kk = 0; kk < 4; ++kk) {
        const float* wr = W3 + (4 * k4 + kk) * 256 + oc;
        acc[0] = fmaf(xv[kk], wr[0], acc[0]);
        acc[1] = fmaf(xv[kk], wr[64], acc[1]);
        acc[2] = fmaf(xv[kk], wr[128], acc[2]);
        acc[3] = fmaf(xv[kk], wr[192], acc[3]);
      }
    }
    __syncthreads();   // reads of h2/xs done before ys overlays ubuf
    #pragma unroll
    for (int oi = 0; oi < 4; ++oi)
      ys[rg * 260 + oc + 64 * oi] = acc[oi] + b3[oc + 64 * oi];
  }
  __syncthreads();

  // ---- iteration-invariant operand fragments (registers) ----
  short8 aah[4], aal[4];         // phase-A A-op: A rows 16T.., K-half kh
  f4v binit = {0.f, 0.f, 0.f, 0.f};
  if (wv < 4) {
    #pragma unroll
    for (int s = 0; s < 4; ++s) {
      const float* ap = A + (size_t)(l15 + 16 * T) * 256 + 128 * kh + 32 * s + 8 * quad;
      float v[8];
      #pragma unroll
      for (int j = 0; j < 8; ++j) v[j] = ap[j];
      split8(v, aah[s], aal[s]);
    }
    if (wv < 2 && l15 < 8) {   // kh==0 carries -b; pad rows get 0
      f4v bv = *(const f4v*)&bmat[(size_t)(row0 + l15) * 32 + 16 * T + 4 * quad];
      binit = -bv;
    }
  }

  short8 kanh[2], kanl[2];       // phase-B A-op: KAT n-tiles U=2wv,2wv+1
  #pragma unroll
  for (int u = 0; u < 2; ++u) {
    const int U = 2 * wv + u;
    const float* kp = KAT + (size_t)(16 * U + l15) * 32 + 8 * quad;
    float v[8];
    #pragma unroll
    for (int j = 0; j < 8; ++j) v[j] = kp[j];
    split8(v, kanh[u], kanl[u]);
  }

  // ---- zfrag write offsets ----
  int zoff[2];
  #pragma unroll
  for (int u = 0; u < 2; ++u) {
    const int U = 2 * wv + u;
    const int qp = 2 * (U & 1) + (quad >> 1);
    zoff[u] = (((U >> 3) * 4 + ((U >> 1) & 3)) * 2) * 256
              + qp * 64 + l15 * 4 + 2 * (quad & 1);
  }

  // ---- init z registers from y; publish zfrag (pad lanes -> zeros) ----
  float zr[2][4];
  #pragma unroll
  for (int u = 0; u < 2; ++u) {
    const int U = 2 * wv + u;
    f4v yv = *(const f4v*)&ys[l15 * 260 + 16 * U + 4 * quad];  // in-bounds of ubuf
    #pragma unroll
    for (int r = 0; r < 4; ++r) zr[u][r] = (l15 < 8) ? yv[r] : 0.f;
    unsigned h0, l0, h1_, l1_;
    split_pair(zr[u][0], zr[u][1], h0, l0);
    split_pair(zr[u][2], zr[u][3], h1_, l1_);
    u2v hv; hv[0] = h0; hv[1] = h1_;
    u2v lv; lv[0] = l0; lv[1] = l1_;
    *(u2v*)&zfrag[zoff[u]] = hv;
    *(u2v*)&zfrag[zoff[u] + 256] = lv;
  }
  __syncthreads();

  const int niter = n_iter_p[0];

  for (int it = 0; it <= niter; ++it) {
    // ======== Phase A (waves 0-3): partial r^T = A z^T - b^T ========
    if (wv < 4) {
      short8 zfh[4], zfl[4];
      #pragma unroll
      for (int s = 0; s < 4; ++s) {
        zfh[s] = *(const short8*)&zfrag[((kh * 4 + s) * 2 + 0) * 256 + lane * 4];
        zfl[s] = *(const short8*)&zfrag[((kh * 4 + s) * 2 + 1) * 256 + lane * 4];
      }
      f4v c0 = binit, c1 = {0.f, 0.f, 0.f, 0.f};
      #pragma unroll
      for (int s = 0; s < 4; ++s) {
        f4v cc = (s & 1) ? c1 : c0;
        cc = mfma16(aah[s], zfh[s], cc);
        cc = mfma16(aal[s], zfh[s], cc);
        cc = mfma16(aah[s], zfl[s], cc);
        if (s & 1) c1 = cc; else c0 = cc;
      }
      f4v rA = c0 + c1;
      unsigned h0, l0, h1_, l1_;
      split_pair(rA[0], rA[1], h0, l0);
      split_pair(rA[2], rA[3], h1_, l1_);
      const int lanep = (2 * T + (quad >> 1)) * 16 + l15;
      const int rb = kh * 512 + lanep * 4 + 2 * (quad & 1);
      u2v hv; hv[0] = h0; hv[1] = h1_;
      u2v lv; lv[0] = l0; lv[1] = l1_;
      *(u2v*)&rfrag[rb] = hv;
      *(u2v*)&rfrag[rb + 256] = lv;
    }
    __syncthreads();

    // ======== Phase B (all waves): w^T = KA^T r^T for U = 2wv, 2wv+1 ========
    const short8 rh0 = *(const short8*)&rfrag[0 * 256 + lane * 4];
    const short8 rl0 = *(const short8*)&rfrag[1 * 256 + lane * 4];
    const short8 rh1 = *(const short8*)&rfrag[2 * 256 + lane * 4];
    const short8 rl1 = *(const short8*)&rfrag[3 * 256 + lane * 4];
    f4v cB[2];
    #pragma unroll
    for (int u = 0; u < 2; ++u) {
      f4v cc = {0.f, 0.f, 0.f, 0.f};
      cc = mfma16(kanh[u], rh0, cc);
      cc = mfma16(kanl[u], rh0, cc);
      cc = mfma16(kanh[u], rl0, cc);
      cc = mfma16(kanh[u], rh1, cc);
      cc = mfma16(kanl[u], rh1, cc);
      cc = mfma16(kanh[u], rl1, cc);
      cB[u] = cc;
    }

    if (it < niter) {
      #pragma unroll
      for (int u = 0; u < 2; ++u) {
        #pragma unroll
        for (int r = 0; r < 4; ++r) {
          float z = zr[u][r], wvv = cB[u][r];
          float vv = fminf(fmaxf(z - 2.f * wvv, 0.f), 1.f);  // clip(2u - z)
          zr[u][r] = fmaf(1.7f, vv - z + wvv, z);            // z += 1.7*(v-u)
        }
        unsigned h0, l0, h1_, l1_;
        split_pair(zr[u][0], zr[u][1], h0, l0);
        split_pair(zr[u][2], zr[u][3], h1_, l1_);
        u2v hv; hv[0] = h0; hv[1] = h1_;
        u2v lv; lv[0] = l0; lv[1] = l1_;
        *(u2v*)&zfrag[zoff[u]] = hv;
        *(u2v*)&zfrag[zoff[u] + 256] = lv;
      }
      __syncthreads();
    } else {
      if (l15 < 8) {
        #pragma unroll
        for (int u = 0; u < 2; ++u) {
          const int U = 2 * wv + u;
          f4v ov;
          #pragma unroll
          for (int r = 0; r < 4; ++r) ov[r] = zr[u][r] - cB[u][r];
          *(f4v*)&out[(size_t)(row0 + l15) * 256 + 16 * U + 4 * quad] = ov;
        }
      }
    }
  }
}

// ---------------------------------------------------------------------------
extern "C" void kernel_launch(void* const* d_in, const int* in_sizes, int n_in,
                              void* d_out, int out_size, void* d_ws, size_t ws_size,
                              hipStream_t stream) {
  const float* x    = (const float*)d_in[0];
  const float* bmat = (const float*)d_in[1];
  const float* W1   = (const float*)d_in[2];
  const float* b1   = (const float*)d_in[3];
  const float* W2   = (const float*)d_in[4];
  const float* b2   = (const float*)d_in[5];
  const float* W3   = (const float*)d_in[6];
  const float* b3   = (const float*)d_in[7];
  const float* A    = (const float*)d_in[8];
  const int*  n_it  = (const int*)d_in[10];
  float* KAT = (float*)d_ws;          // 256*32 floats = 32 KB
  float* out = (float*)d_out;

  hipLaunchKernelGGL(k_prep, dim3(1), dim3(256), 0, stream, A, KAT);
  hipLaunchKernelGGL(k_main, dim3(Bn / TR), dim3(512), 0, stream,
                     x, bmat, W1, b1, W2, b2, W3, b3, A, KAT, n_it, out);
}

// Round 8
// 220.979 us; speedup vs baseline: 2.0916x; 1.2429x over previous
//
#include <hip/hip_runtime.h>
#include <hip/hip_bf16.h>

typedef float    f4v    __attribute__((ext_vector_type(4)));
typedef short    short8 __attribute__((ext_vector_type(8)));
typedef unsigned u2v    __attribute__((ext_vector_type(2)));

constexpr int Bn = 4096, TR = 16;

// ---- split-bf16 helpers ----------------------------------------------------
__device__ inline unsigned cvt2(float x, float y) {
  union { __hip_bfloat162 h; unsigned u; } c;
  c.h = __float22bfloat162_rn(float2{x, y});
  return c.u;   // low16 = bf16(x), high16 = bf16(y)
}
__device__ inline void split_pair(float x, float y, unsigned& hp, unsigned& lp) {
  hp = cvt2(x, y);
  float hx = __uint_as_float(hp << 16);
  float hy = __uint_as_float(hp & 0xffff0000u);
  lp = cvt2(x - hx, y - hy);
}
union S8U { unsigned u[4]; short8 s; };
__device__ inline void split8(const float v[8], short8& hi, short8& lo) {
  S8U h, l;
  #pragma unroll
  for (int d = 0; d < 4; ++d) split_pair(v[2 * d], v[2 * d + 1], h.u[d], l.u[d]);
  hi = h.s; lo = l.s;
}
__device__ inline void split8p(const float* p, short8& hi, short8& lo) {
  f4v a = *(const f4v*)p, b = *(const f4v*)(p + 4);
  float v[8] = {a[0], a[1], a[2], a[3], b[0], b[1], b[2], b[3]};
  split8(v, hi, lo);
}
__device__ inline f4v mfma16(short8 a, short8 b, f4v c) {
  return __builtin_amdgcn_mfma_f32_16x16x32_bf16(a, b, c, 0, 0, 0);
}
__device__ __attribute__((always_inline)) inline f4v gdot8(
    const short8 (&ah)[8], const short8 (&al)[8],
    const short8 (&bh)[8], const short8 (&bl)[8]) {
  f4v c = {0.f, 0.f, 0.f, 0.f};
  #pragma unroll
  for (int s = 0; s < 8; ++s) {
    c = mfma16(ah[s], bh[s], c);
    c = mfma16(al[s], bh[s], c);
    c = mfma16(ah[s], bl[s], c);
  }
  return c;
}

// ---------------------------------------------------------------------------
// k_prep: KAT[n][m] = (inv(A A^T + 1e-6 I) @ A)^T -> d_ws. 1 block, 256 thr.
// G via split-bf16 MFMA; Gauss-Jordan on wave 0 via unrolled shuffles.
// ---------------------------------------------------------------------------
__global__ __launch_bounds__(256) void k_prep(const float* __restrict__ A,
                                              float* __restrict__ KAT) {
  __shared__ __align__(16) float As[32 * 256];
  __shared__ float Gm[32 * 68];
  __shared__ float GinvL[32 * 32];

  const int t = threadIdx.x;
  const int lane = t & 63, wv = t >> 6, quad = lane >> 4, l15 = lane & 15;
  const int T = wv & 1, kh = wv >> 1;

  for (int i = t; i < 2048; i += 256)
    ((f4v*)As)[i] = ((const f4v*)A)[i];
  __syncthreads();

  // G = A A^T (+ eps I): wave = 16x16 tile (rows 16T.., cols 16kh..)
  {
    short8 afh[2][8], afl[2][8];
    #pragma unroll
    for (int tt = 0; tt < 2; ++tt)
      #pragma unroll
      for (int s = 0; s < 8; ++s)
        split8p(As + (l15 + 16 * tt) * 256 + 32 * s + 8 * quad,
                afh[tt][s], afl[tt][s]);
    f4v cg;
    if      (wv == 0) cg = gdot8(afh[0], afl[0], afh[0], afl[0]);
    else if (wv == 1) cg = gdot8(afh[1], afl[1], afh[0], afl[0]);
    else if (wv == 2) cg = gdot8(afh[0], afl[0], afh[1], afl[1]);
    else              cg = gdot8(afh[1], afl[1], afh[1], afl[1]);
    #pragma unroll
    for (int r = 0; r < 4; ++r) {
      int gi = 16 * T + 4 * quad + r, gj = 16 * kh + l15;
      Gm[gi * 68 + gj]      = cg[r] + (gi == gj ? 1e-6f : 0.f);
      Gm[gi * 68 + 32 + gj] = (gi == gj) ? 1.f : 0.f;
    }
  }
  __syncthreads();

  // Gauss-Jordan on wave 0: lane = augmented column, fully unrolled
  if (wv == 0) {
    float gcol[32];
    #pragma unroll
    for (int i = 0; i < 32; ++i) gcol[i] = Gm[i * 68 + lane];
    #pragma unroll
    for (int k = 0; k < 32; ++k) {
      float ckk  = __shfl(gcol[k], k);
      float ipiv = 1.f / ckk;
      float pivj = gcol[k] * ipiv;
      gcol[k] = pivj;
      #pragma unroll
      for (int i = 0; i < 32; ++i) {
        if (i == k) continue;
        float cki = __shfl(gcol[i], k);
        gcol[i] = fmaf(-cki, pivj, gcol[i]);
      }
    }
    if (lane >= 32) {
      #pragma unroll
      for (int i = 0; i < 32; ++i) GinvL[i * 32 + (lane - 32)] = gcol[i];
    }
  }
  __syncthreads();

  // KAT[n=t][m] = sum_p As[p][n] * Ginv[p][m]
  {
    float res[32];
    #pragma unroll
    for (int m = 0; m < 32; ++m) res[m] = 0.f;
    for (int p = 0; p < 32; ++p) {
      float av = As[p * 256 + t];
      #pragma unroll
      for (int m4 = 0; m4 < 8; ++m4) {
        f4v g = *(const f4v*)&GinvL[p * 32 + 4 * m4];
        res[4 * m4 + 0] = fmaf(av, g[0], res[4 * m4 + 0]);
        res[4 * m4 + 1] = fmaf(av, g[1], res[4 * m4 + 1]);
        res[4 * m4 + 2] = fmaf(av, g[2], res[4 * m4 + 2]);
        res[4 * m4 + 3] = fmaf(av, g[3], res[4 * m4 + 3]);
      }
    }
    #pragma unroll
    for (int m4 = 0; m4 < 8; ++m4) {
      f4v v = {res[4 * m4], res[4 * m4 + 1], res[4 * m4 + 2], res[4 * m4 + 3]};
      *(f4v*)&KAT[t * 32 + 4 * m4] = v;
    }
  }
}

// ---------------------------------------------------------------------------
// k_main: 512 threads (8 waves), TR=16, grid 256 (full lanes, no padding).
// Phase A (waves 0,1 = T): FULL-K r^T = A z^T - b^T, 24 MFMA into 4 accums.
// Single (non-partial) rfrag -> phase B is 2 reads + 3 MFMA per U-tile.
// Phase B (all 8 waves): U = 2wv, 2wv+1: w^T = KA^T r^T; z update in regs.
// ---------------------------------------------------------------------------
__global__ __launch_bounds__(512, 1) void k_main(
    const float* __restrict__ x,  const float* __restrict__ bmat,
    const float* __restrict__ W1, const float* __restrict__ b1,
    const float* __restrict__ W2, const float* __restrict__ b2,
    const float* __restrict__ W3, const float* __restrict__ b3,
    const float* __restrict__ A,  const float* __restrict__ KAT,
    const int* __restrict__ n_iter_p, float* __restrict__ out) {

  __shared__ __align__(16) float    ubuf[8768];    // MLP scratch; later y[16][260]
  __shared__ __align__(16) unsigned zfrag[4096];   // [s=0..7][hi/lo][1KB frag]
  __shared__ __align__(16) unsigned rfrag[512];    // [hi/lo][1KB frag]

  const int t = threadIdx.x;
  const int lane = t & 63, wv = t >> 6, quad = lane >> 4, l15 = lane & 15;
  const int row0 = blockIdx.x * TR;

  float* xs = ubuf;            // [16][132]
  float* h1 = ubuf + 2112;     // [16][208]
  float* h2 = ubuf + 5440;     // [16][208]
  float* ys = ubuf;            // [16][260] (xs+h1 dead by then)

  if (t < 512) {
    int r = t >> 5, c4 = t & 31;
    *(f4v*)&xs[r * 132 + 4 * c4] = *(const f4v*)&x[(size_t)(row0 + r) * 128 + 4 * c4];
  }
  __syncthreads();

  // ---- MLP: 2 rows per wave ----
  {
    const int rg = wv, oc = lane;
    const bool g3 = (oc < 8);    // HID=200: col oc+192 valid iff oc<8
    float acc[4][2];

    // L1: 128 -> 200, relu
    #pragma unroll
    for (int oi = 0; oi < 4; ++oi) { acc[oi][0] = 0.f; acc[oi][1] = 0.f; }
    for (int k4 = 0; k4 < 32; ++k4) {
      f4v xv0 = *(const f4v*)&xs[(2 * rg + 0) * 132 + 4 * k4];
      f4v xv1 = *(const f4v*)&xs[(2 * rg + 1) * 132 + 4 * k4];
      #pragma unroll
      for (int kk = 0; kk < 4; ++kk) {
        const float* wr = W1 + (4 * k4 + kk) * 200 + oc;
        float w0 = wr[0], w1c = wr[64], w2c = wr[128];
        float w3c = g3 ? wr[192] : 0.f;
        acc[0][0] = fmaf(xv0[kk], w0, acc[0][0]);  acc[0][1] = fmaf(xv1[kk], w0, acc[0][1]);
        acc[1][0] = fmaf(xv0[kk], w1c, acc[1][0]); acc[1][1] = fmaf(xv1[kk], w1c, acc[1][1]);
        acc[2][0] = fmaf(xv0[kk], w2c, acc[2][0]); acc[2][1] = fmaf(xv1[kk], w2c, acc[2][1]);
        acc[3][0] = fmaf(xv0[kk], w3c, acc[3][0]); acc[3][1] = fmaf(xv1[kk], w3c, acc[3][1]);
      }
    }
    #pragma unroll
    for (int oi = 0; oi < 4; ++oi) {
      if (oi == 3 && !g3) continue;
      float bb = b1[oc + 64 * oi];
      h1[(2 * rg + 0) * 208 + oc + 64 * oi] = fmaxf(acc[oi][0] + bb, 0.f);
      h1[(2 * rg + 1) * 208 + oc + 64 * oi] = fmaxf(acc[oi][1] + bb, 0.f);
    }
    __syncthreads();

    // L2: 200 -> 200, relu
    #pragma unroll
    for (int oi = 0; oi < 4; ++oi) { acc[oi][0] = 0.f; acc[oi][1] = 0.f; }
    for (int k4 = 0; k4 < 50; ++k4) {
      f4v xv0 = *(const f4v*)&h1[(2 * rg + 0) * 208 + 4 * k4];
      f4v xv1 = *(const f4v*)&h1[(2 * rg + 1) * 208 + 4 * k4];
      #pragma unroll
      for (int kk = 0; kk < 4; ++kk) {
        const float* wr = W2 + (4 * k4 + kk) * 200 + oc;
        float w0 = wr[0], w1c = wr[64], w2c = wr[128];
        float w3c = g3 ? wr[192] : 0.f;
        acc[0][0] = fmaf(xv0[kk], w0, acc[0][0]);  acc[0][1] = fmaf(xv1[kk], w0, acc[0][1]);
        acc[1][0] = fmaf(xv0[kk], w1c, acc[1][0]); acc[1][1] = fmaf(xv1[kk], w1c, acc[1][1]);
        acc[2][0] = fmaf(xv0[kk], w2c, acc[2][0]); acc[2][1] = fmaf(xv1[kk], w2c, acc[2][1]);
        acc[3][0] = fmaf(xv0[kk], w3c, acc[3][0]); acc[3][1] = fmaf(xv1[kk], w3c, acc[3][1]);
      }
    }
    #pragma unroll
    for (int oi = 0; oi < 4; ++oi) {
      if (oi == 3 && !g3) continue;
      float bb = b2[oc + 64 * oi];
      h2[(2 * rg + 0) * 208 + oc + 64 * oi] = fmaxf(acc[oi][0] + bb, 0.f);
      h2[(2 * rg + 1) * 208 + oc + 64 * oi] = fmaxf(acc[oi][1] + bb, 0.f);
    }
    __syncthreads();

    // L3: 200 -> 256 (no relu) -> ys
    #pragma unroll
    for (int oi = 0; oi < 4; ++oi) { acc[oi][0] = 0.f; acc[oi][1] = 0.f; }
    for (int k4 = 0; k4 < 50; ++k4) {
      f4v xv0 = *(const f4v*)&h2[(2 * rg + 0) * 208 + 4 * k4];
      f4v xv1 = *(const f4v*)&h2[(2 * rg + 1) * 208 + 4 * k4];
      #pragma unroll
      for (int kk = 0; kk < 4; ++kk) {
        const float* wr = W3 + (4 * k4 + kk) * 256 + oc;
        float w0 = wr[0], w1c = wr[64], w2c = wr[128], w3c = wr[192];
        acc[0][0] = fmaf(xv0[kk], w0, acc[0][0]);  acc[0][1] = fmaf(xv1[kk], w0, acc[0][1]);
        acc[1][0] = fmaf(xv0[kk], w1c, acc[1][0]); acc[1][1] = fmaf(xv1[kk], w1c, acc[1][1]);
        acc[2][0] = fmaf(xv0[kk], w2c, acc[2][0]); acc[2][1] = fmaf(xv1[kk], w2c, acc[2][1]);
        acc[3][0] = fmaf(xv0[kk], w3c, acc[3][0]); acc[3][1] = fmaf(xv1[kk], w3c, acc[3][1]);
      }
    }
    __syncthreads();   // reads of h2/xs done before ys overlays ubuf
    #pragma unroll
    for (int oi = 0; oi < 4; ++oi) {
      float bb = b3[oc + 64 * oi];
      ys[(2 * rg + 0) * 260 + oc + 64 * oi] = acc[oi][0] + bb;
      ys[(2 * rg + 1) * 260 + oc + 64 * oi] = acc[oi][1] + bb;
    }
  }
  __syncthreads();

  // ---- iteration-invariant operand fragments (registers) ----
  const int T = wv;              // phase-A m-tile for waves 0,1
  short8 aah[8], aal[8];         // phase-A A-op: A rows 16T.., FULL K (8 steps)
  f4v binit = {0.f, 0.f, 0.f, 0.f};
  if (wv < 2) {
    #pragma unroll
    for (int s = 0; s < 8; ++s) {
      const float* ap = A + (size_t)(l15 + 16 * T) * 256 + 32 * s + 8 * quad;
      float v[8];
      #pragma unroll
      for (int j = 0; j < 8; ++j) v[j] = ap[j];
      split8(v, aah[s], aal[s]);
    }
    f4v bv = *(const f4v*)&bmat[(size_t)(row0 + l15) * 32 + 16 * T + 4 * quad];
    binit = -bv;
  }

  short8 kanh[2], kanl[2];       // phase-B A-op: KAT n-tiles U=2wv,2wv+1
  #pragma unroll
  for (int u = 0; u < 2; ++u) {
    const int U = 2 * wv + u;
    const float* kp = KAT + (size_t)(16 * U + l15) * 32 + 8 * quad;
    float v[8];
    #pragma unroll
    for (int j = 0; j < 8; ++j) v[j] = kp[j];
    split8(v, kanh[u], kanl[u]);
  }

  // ---- zfrag write offsets (B-op fragment order, derived from U) ----
  int zoff[2];
  #pragma unroll
  for (int u = 0; u < 2; ++u) {
    const int U = 2 * wv + u;
    const int qp = 2 * (U & 1) + (quad >> 1);
    zoff[u] = (((U >> 3) * 4 + ((U >> 1) & 3)) * 2) * 256
              + qp * 64 + l15 * 4 + 2 * (quad & 1);
  }

  // ---- init z registers from y; publish zfrag ----
  float zr[2][4];
  #pragma unroll
  for (int u = 0; u < 2; ++u) {
    const int U = 2 * wv + u;
    f4v yv = *(const f4v*)&ys[l15 * 260 + 16 * U + 4 * quad];
    #pragma unroll
    for (int r = 0; r < 4; ++r) zr[u][r] = yv[r];
    unsigned h0, l0, h1_, l1_;
    split_pair(zr[u][0], zr[u][1], h0, l0);
    split_pair(zr[u][2], zr[u][3], h1_, l1_);
    u2v hv; hv[0] = h0; hv[1] = h1_;
    u2v lv; lv[0] = l0; lv[1] = l1_;
    *(u2v*)&zfrag[zoff[u]] = hv;
    *(u2v*)&zfrag[zoff[u] + 256] = lv;
  }
  __syncthreads();

  const int niter = n_iter_p[0];

  for (int it = 0; it <= niter; ++it) {
    // ======== Phase A (waves 0,1): full-K r^T = A z^T - b^T ========
    if (wv < 2) {
      short8 zfh[8], zfl[8];
      #pragma unroll
      for (int s = 0; s < 8; ++s) {
        zfh[s] = *(const short8*)&zfrag[(s * 2 + 0) * 256 + lane * 4];
        zfl[s] = *(const short8*)&zfrag[(s * 2 + 1) * 256 + lane * 4];
      }
      f4v c0 = binit;
      f4v c1 = {0.f, 0.f, 0.f, 0.f};
      f4v c2 = {0.f, 0.f, 0.f, 0.f};
      f4v c3 = {0.f, 0.f, 0.f, 0.f};
      #pragma unroll
      for (int s4 = 0; s4 < 2; ++s4) {   // 4 independent accumulator chains
        int s = 4 * s4;
        c0 = mfma16(aah[s+0], zfh[s+0], c0);
        c1 = mfma16(aah[s+1], zfh[s+1], c1);
        c2 = mfma16(aah[s+2], zfh[s+2], c2);
        c3 = mfma16(aah[s+3], zfh[s+3], c3);
        c0 = mfma16(aal[s+0], zfh[s+0], c0);
        c1 = mfma16(aal[s+1], zfh[s+1], c1);
        c2 = mfma16(aal[s+2], zfh[s+2], c2);
        c3 = mfma16(aal[s+3], zfh[s+3], c3);
        c0 = mfma16(aah[s+0], zfl[s+0], c0);
        c1 = mfma16(aah[s+1], zfl[s+1], c1);
        c2 = mfma16(aah[s+2], zfl[s+2], c2);
        c3 = mfma16(aah[s+3], zfl[s+3], c3);
      }
      f4v rA = (c0 + c1) + (c2 + c3);
      unsigned h0, l0, h1_, l1_;
      split_pair(rA[0], rA[1], h0, l0);
      split_pair(rA[2], rA[3], h1_, l1_);
      const int rb = (2 * T + (quad >> 1)) * 64 + l15 * 4 + 2 * (quad & 1);
      u2v hv; hv[0] = h0; hv[1] = h1_;
      u2v lv; lv[0] = l0; lv[1] = l1_;
      *(u2v*)&rfrag[rb] = hv;
      *(u2v*)&rfrag[rb + 256] = lv;
    }
    __syncthreads();

    // ======== Phase B (all waves): w^T = KA^T r^T for U = 2wv, 2wv+1 ========
    const short8 rh = *(const short8*)&rfrag[0 * 256 + lane * 4];
    const short8 rl = *(const short8*)&rfrag[1 * 256 + lane * 4];
    f4v cB[2];
    #pragma unroll
    for (int u = 0; u < 2; ++u) {
      f4v cc = {0.f, 0.f, 0.f, 0.f};
      cc = mfma16(kanh[u], rh, cc);
      cc = mfma16(kanl[u], rh, cc);
      cc = mfma16(kanh[u], rl, cc);
      cB[u] = cc;
    }

    if (it < niter) {
      #pragma unroll
      for (int u = 0; u < 2; ++u) {
        #pragma unroll
        for (int r = 0; r < 4; ++r) {
          float z = zr[u][r], wvv = cB[u][r];
          float vv = fminf(fmaxf(z - 2.f * wvv, 0.f), 1.f);  // clip(2u - z)
          zr[u][r] = fmaf(1.7f, vv - z + wvv, z);            // z += 1.7*(v-u)
        }
        unsigned h0, l0, h1_, l1_;
        split_pair(zr[u][0], zr[u][1], h0, l0);
        split_pair(zr[u][2], zr[u][3], h1_, l1_);
        u2v hv; hv[0] = h0; hv[1] = h1_;
        u2v lv; lv[0] = l0; lv[1] = l1_;
        *(u2v*)&zfrag[zoff[u]] = hv;
        *(u2v*)&zfrag[zoff[u] + 256] = lv;
      }
      __syncthreads();
    } else {
      #pragma unroll
      for (int u = 0; u < 2; ++u) {
        const int U = 2 * wv + u;
        f4v ov;
        #pragma unroll
        for (int r = 0; r < 4; ++r) ov[r] = zr[u][r] - cB[u][r];
        *(f4v*)&out[(size_t)(row0 + l15) * 256 + 16 * U + 4 * quad] = ov;
      }
    }
  }
}

// ---------------------------------------------------------------------------
extern "C" void kernel_launch(void* const* d_in, const int* in_sizes, int n_in,
                              void* d_out, int out_size, void* d_ws, size_t ws_size,
                              hipStream_t stream) {
  const float* x    = (const float*)d_in[0];
  const float* bmat = (const float*)d_in[1];
  const float* W1   = (const float*)d_in[2];
  const float* b1   = (const float*)d_in[3];
  const float* W2   = (const float*)d_in[4];
  const float* b2   = (const float*)d_in[5];
  const float* W3   = (const float*)d_in[6];
  const float* b3   = (const float*)d_in[7];
  const float* A    = (const float*)d_in[8];
  const int*  n_it  = (const int*)d_in[10];
  float* KAT = (float*)d_ws;          // 256*32 floats = 32 KB
  float* out = (float*)d_out;

  hipLaunchKernelGGL(k_prep, dim3(1), dim3(256), 0, stream, A, KAT);
  hipLaunchKernelGGL(k_main, dim3(Bn / TR), dim3(512), 0, stream,
                     x, bmat, W1, b1, W2, b2, W3, b3, A, KAT, n_it, out);
}